// Round 8
// baseline (4483.419 us; speedup 1.0000x reference)
//
#include <hip/hip_runtime.h>

#define N_NODES 16384
#define N_EDGES 524288
#define BAND_I 16      // rows per block
#define CHUNK_J 1024   // 4 waves x 256 j per chunk
#define N_CHUNKS 8     // chunks per block; 2 blocks per i-band
// grid = 1024 bands * 2 = 2048 persistent blocks

typedef float f32x4 __attribute__((ext_vector_type(4)));

// ---------------- kernel 1: scatter-add neighbor features ----------------
__global__ void scatter_kernel(const int* __restrict__ eidx,
                               const float* __restrict__ x,
                               float* __restrict__ agg) {
    int e = blockIdx.x * blockDim.x + threadIdx.x;
    if (e >= N_EDGES) return;
    int s = eidx[e];            // src row
    int t = eidx[N_EDGES + e];  // tgt row
    float f0 = x[s * 3 + 0];
    float f1 = x[s * 3 + 1];
    float f2 = x[s * 3 + 2];
    atomicAdd(&agg[t * 3 + 0], f0);
    atomicAdd(&agg[t * 3 + 1], f1);
    atomicAdd(&agg[t * 3 + 2], f2);
}

// ---------------- kernel 2: GIN MLP per node -> h [N,16] ----------------
__global__ void mlp_kernel(const float* __restrict__ x,
                           const float* __restrict__ agg,
                           const float* __restrict__ W1,
                           const float* __restrict__ b1,
                           const float* __restrict__ W2,
                           const float* __restrict__ b2,
                           const float* __restrict__ eps_p,
                           float* __restrict__ h) {
    int n = blockIdx.x * blockDim.x + threadIdx.x;
    if (n >= N_NODES) return;
    float se = 1.0f + eps_p[0];
    float z0 = se * x[n * 3 + 0] + agg[n * 3 + 0];
    float z1 = se * x[n * 3 + 1] + agg[n * 3 + 1];
    float z2 = se * x[n * 3 + 2] + agg[n * 3 + 2];
    float h1[16];
#pragma unroll
    for (int j = 0; j < 16; ++j) {
        float a = b1[j];
        a += z0 * W1[0 * 16 + j];
        a += z1 * W1[1 * 16 + j];
        a += z2 * W1[2 * 16 + j];
        h1[j] = fmaxf(a, 0.0f);
    }
    float4* h4 = (float4*)&h[n * 16];
#pragma unroll
    for (int oq = 0; oq < 4; ++oq) {
        float4 o;
        float* op = (float*)&o;
#pragma unroll
        for (int c = 0; c < 4; ++c) {
            int oo = oq * 4 + c;
            float a = b2[oo];
#pragma unroll
            for (int j = 0; j < 16; ++j) a += h1[j] * W2[j * 16 + oo];
            op[c] = fmaxf(a, 0.0f);
        }
        h4[oq] = o;
    }
}

// ---------------- kernel 3: out[i][j] = dot(h[i], h[j]) ----------------
// PERSISTENT blocks: 2048 blocks x 256 threads. Each block owns a 16-row
// i-band half: stages hi once (1 KB LDS, one barrier), then loops 8 j-chunks
// of 1024 j with NO further barriers. Chunk c+1's independent L2 loads issue
// while chunk c's NT stores are in flight; endpgm store-drain paid once per
// block instead of once per tile (R3-R7 ran 8192 short-lived blocks).
__global__ __launch_bounds__(256) void pairwise_kernel(const float* __restrict__ h,
                                                       float* __restrict__ out) {
    __shared__ float hi[BAND_I * 16];   // 1 KB
    const int band = blockIdx.x >> 1;
    const int half = blockIdx.x & 1;
    const int i0 = band * BAND_I;
    const int tid = threadIdx.x;

    // stage hi panel: 16 rows x 4 f32x4 = 64 f32x4
    if (tid < BAND_I * 4) {
        ((f32x4*)hi)[tid] = ((const f32x4*)h)[(size_t)i0 * 4 + tid];
    }
    __syncthreads();

    const f32x4* hg = (const f32x4*)h;
    f32x4* out4 = (f32x4*)out;

#pragma unroll 1
    for (int c = 0; c < N_CHUNKS; ++c) {
        const int jbase = (half * N_CHUNKS + c) * CHUNK_J + tid * 4;

        // load hj: 4 consecutive j-rows from L2-resident h, transpose to
        // k-major f32x4 in registers (17 independent loads incl. none here).
        f32x4 hj[16];
#pragma unroll
        for (int jj = 0; jj < 4; ++jj) {
            const size_t jb4 = (size_t)(jbase + jj) * 4;
            f32x4 q0 = hg[jb4 + 0];
            f32x4 q1 = hg[jb4 + 1];
            f32x4 q2 = hg[jb4 + 2];
            f32x4 q3 = hg[jb4 + 3];
            hj[0][jj]  = q0.x;  hj[1][jj]  = q0.y;  hj[2][jj]  = q0.z;  hj[3][jj]  = q0.w;
            hj[4][jj]  = q1.x;  hj[5][jj]  = q1.y;  hj[6][jj]  = q1.z;  hj[7][jj]  = q1.w;
            hj[8][jj]  = q2.x;  hj[9][jj]  = q2.y;  hj[10][jj] = q2.z;  hj[11][jj] = q2.w;
            hj[12][jj] = q3.x;  hj[13][jj] = q3.y;  hj[14][jj] = q3.z;  hj[15][jj] = q3.w;
        }

        const size_t ob = (size_t)i0 * (N_NODES / 4) + (size_t)(jbase >> 2);
#pragma unroll
        for (int r = 0; r < BAND_I; ++r) {
            const f32x4* hr = (const f32x4*)&hi[r * 16];
            f32x4 a0 = hr[0], a1 = hr[1], a2 = hr[2], a3 = hr[3];
            f32x4 acc = a0.x * hj[0];
            acc += a0.y * hj[1];
            acc += a0.z * hj[2];
            acc += a0.w * hj[3];
            acc += a1.x * hj[4];
            acc += a1.y * hj[5];
            acc += a1.z * hj[6];
            acc += a1.w * hj[7];
            acc += a2.x * hj[8];
            acc += a2.y * hj[9];
            acc += a2.z * hj[10];
            acc += a2.w * hj[11];
            acc += a3.x * hj[12];
            acc += a3.y * hj[13];
            acc += a3.z * hj[14];
            acc += a3.w * hj[15];
            __builtin_nontemporal_store(acc, &out4[ob + (size_t)r * (N_NODES / 4)]);
        }
    }
}

extern "C" void kernel_launch(void* const* d_in, const int* in_sizes, int n_in,
                              void* d_out, int out_size, void* d_ws, size_t ws_size,
                              hipStream_t stream) {
    const float* node_feats = (const float*)d_in[0];
    const int*   edge_idx   = (const int*)d_in[1];
    const float* W1         = (const float*)d_in[2];
    const float* b1         = (const float*)d_in[3];
    const float* W2         = (const float*)d_in[4];
    const float* b2         = (const float*)d_in[5];
    const float* eps        = (const float*)d_in[6];
    float* out = (float*)d_out;

    // workspace layout: agg [N*3 floats] at 0, h [N*16 floats] at 256 KB
    float* agg = (float*)d_ws;
    float* h   = (float*)((char*)d_ws + 262144);

    hipMemsetAsync(agg, 0, N_NODES * 3 * sizeof(float), stream);
    scatter_kernel<<<N_EDGES / 256, 256, 0, stream>>>(edge_idx, node_feats, agg);
    mlp_kernel<<<N_NODES / 256, 256, 0, stream>>>(node_feats, agg, W1, b1, W2, b2, eps, h);

    pairwise_kernel<<<2048, 256, 0, stream>>>(h, out);
}